// Round 2
// baseline (196.502 us; speedup 1.0000x reference)
//
#include <hip/hip_runtime.h>
#include <hip/hip_bf16.h>

// Problem constants
#define BB 8
#define TT 2048
#define EE 1024
#define HH 64

typedef __attribute__((ext_vector_type(8))) short short8;
typedef __attribute__((ext_vector_type(4))) float f32x4;

__device__ inline f32x4 mfma_16x16x32(short8 a, short8 b, f32x4 c) {
  return __builtin_amdgcn_mfma_f32_16x16x32_bf16(a, b, c, 0, 0, 0);
}

// async global->LDS, 16B per lane, LDS dest = wave-uniform base + lane*16
__device__ inline void gload_lds16(const __hip_bfloat16* g, __hip_bfloat16* l) {
  __builtin_amdgcn_global_load_lds((const __attribute__((address_space(1))) void*)g,
                                   (__attribute__((address_space(3))) void*)l,
                                   16, 0, 0);
}

__device__ inline short f2bf(float f) {
  __hip_bfloat16 h = __float2bfloat16(f);
  return *reinterpret_cast<short*>(&h);
}
__device__ inline float bf2f(short s) {
  __hip_bfloat16 h = *reinterpret_cast<__hip_bfloat16*>(&s);
  return __bfloat162float(h);
}

// ---------------------------------------------------------------------------
// Kernel 0: split-precision transposed weights.
// Wthi/Wtlo[n][e]: hi = bf16(W), lo = bf16(W - hi). n in [0,192), e in [0,1024).
// ---------------------------------------------------------------------------
__global__ void prep_w(const float* __restrict__ Wq, const float* __restrict__ Wk,
                       const float* __restrict__ Wv,
                       __hip_bfloat16* __restrict__ Wthi,
                       __hip_bfloat16* __restrict__ Wtlo) {
  const int n = blockIdx.x;          // 0..191
  const int m = n >> 6;
  const int h = n & 63;
  const float* W = (m == 0) ? Wq : (m == 1) ? Wk : Wv;
  const int e0 = threadIdx.x * 4;    // 256 threads * 4 = 1024
#pragma unroll
  for (int j = 0; j < 4; ++j) {
    const float w = W[(e0 + j) * 64 + h];
    const __hip_bfloat16 hi = __float2bfloat16(w);
    Wthi[n * 1024 + e0 + j] = hi;
    Wtlo[n * 1024 + e0 + j] = __float2bfloat16(w - __bfloat162float(hi));
  }
}

// ---------------------------------------------------------------------------
// Kernel A: split-bf16 fp32-emulated GEMM: q|k|v = x @ [Wq|Wk|Wv].
// M=16384, K=1024, N=192. 256 blocks x 64 rows, K-chunk 64, double-buffered
// LDS, reg-prefetch for x (split into hi/lo on the fly), global_load_lds (16B)
// for Wt hi/lo with XOR swizzle. acc = xh*wh + xh*wl + xl*wh (lo*lo dropped).
// Outputs: qhi/qlo, khi/klo [t][h] bf16 pairs; vT[b][h][t] single bf16.
// ---------------------------------------------------------------------------
__global__ __launch_bounds__(256) void qkv_gemm(
    const float* __restrict__ x,
    const __hip_bfloat16* __restrict__ Wthi, const __hip_bfloat16* __restrict__ Wtlo,
    __hip_bfloat16* __restrict__ qhi, __hip_bfloat16* __restrict__ qlo,
    __hip_bfloat16* __restrict__ khi, __hip_bfloat16* __restrict__ klo,
    __hip_bfloat16* __restrict__ vT) {
  __shared__ __hip_bfloat16 Ahi[2][64 * 72];    // 64 rows x 64 k, pad to 72
  __shared__ __hip_bfloat16 Alo[2][64 * 72];
  __shared__ __hip_bfloat16 Bhi[2][192 * 64];   // 192 n-rows x 64 k, swizzled
  __shared__ __hip_bfloat16 Blo[2][192 * 64];

  const int tid  = threadIdx.x;
  const int wave = tid >> 6;
  const int lane = tid & 63;
  const int row0 = blockIdx.x * 64;

  // x staging: each thread loads 16 consecutive floats of one row per chunk
  const int lr = tid >> 2;           // 0..63 local row
  const int le = (tid & 3) * 16;     // 0/16/32/48 within 64-wide k-chunk
  const float* xrow = x + (row0 + lr) * 1024 + le;

  f32x4 acc[12];
#pragma unroll
  for (int j = 0; j < 12; ++j) acc[j] = f32x4{0.f, 0.f, 0.f, 0.f};

  const int l15 = lane & 15, l4 = lane >> 4;

  // issue B (weights hi+lo) async loads for chunk c into buffers [buf]
  // lane i of instr q: n = q*8 + i/8, k-group g = (i&7) ^ (n&7), slot (i&7)
  auto issue_B = [&](int c, int buf) {
    const int g = (lane & 7) ^ ((lane >> 3) & 7);
#pragma unroll
    for (int s = 0; s < 6; ++s) {
      const int qq = wave * 6 + s;                   // 0..23 (8 n-rows each)
      const int n  = qq * 8 + (lane >> 3);
      gload_lds16(Wthi + n * 1024 + c * 64 + g * 8, &Bhi[buf][qq * 512]);
      gload_lds16(Wtlo + n * 1024 + c * 64 + g * 8, &Blo[buf][qq * 512]);
    }
  };
  auto write_A = [&](int buf, const f32x4* xr) {
    short8 h0, h1, l0, l1;
    const float* xf = (const float*)xr;
#pragma unroll
    for (int j = 0; j < 8; ++j) {
      const float v = xf[j];
      const short h = f2bf(v);
      h0[j] = h;
      l0[j] = f2bf(v - bf2f(h));
    }
#pragma unroll
    for (int j = 0; j < 8; ++j) {
      const float v = xf[8 + j];
      const short h = f2bf(v);
      h1[j] = h;
      l1[j] = f2bf(v - bf2f(h));
    }
    *(short8*)&Ahi[buf][lr * 72 + le]     = h0;
    *(short8*)&Ahi[buf][lr * 72 + le + 8] = h1;
    *(short8*)&Alo[buf][lr * 72 + le]     = l0;
    *(short8*)&Alo[buf][lr * 72 + le + 8] = l1;
  };
  auto compute = [&](int buf) {
    const int tr = wave * 16 + l15;
    short8 ah0 = *(const short8*)&Ahi[buf][tr * 72 + l4 * 8];
    short8 ah1 = *(const short8*)&Ahi[buf][tr * 72 + 32 + l4 * 8];
    short8 al0 = *(const short8*)&Alo[buf][tr * 72 + l4 * 8];
    short8 al1 = *(const short8*)&Alo[buf][tr * 72 + 32 + l4 * 8];
#pragma unroll
    for (int j = 0; j < 12; ++j) {
      const int n  = j * 16 + l15;
      const int o0 = ((l4)     ^ (n & 7)) * 8;
      const int o1 = ((4 + l4) ^ (n & 7)) * 8;
      short8 bh0 = *(const short8*)&Bhi[buf][n * 64 + o0];
      short8 bh1 = *(const short8*)&Bhi[buf][n * 64 + o1];
      short8 bl0 = *(const short8*)&Blo[buf][n * 64 + o0];
      short8 bl1 = *(const short8*)&Blo[buf][n * 64 + o1];
      acc[j] = mfma_16x16x32(ah0, bh0, acc[j]);
      acc[j] = mfma_16x16x32(ah1, bh1, acc[j]);
      acc[j] = mfma_16x16x32(ah0, bl0, acc[j]);
      acc[j] = mfma_16x16x32(ah1, bl1, acc[j]);
      acc[j] = mfma_16x16x32(al0, bh0, acc[j]);
      acc[j] = mfma_16x16x32(al1, bh1, acc[j]);
    }
  };

  // ---- prologue ----
  f32x4 xr[4], xn[4];
  {
    const f32x4* p = (const f32x4*)xrow;
    xr[0] = p[0]; xr[1] = p[1]; xr[2] = p[2]; xr[3] = p[3];
  }
  issue_B(0, 0);
  __builtin_amdgcn_s_waitcnt(0);
  write_A(0, xr);
  __syncthreads();

  // ---- main loop ----
  for (int c = 0; c < 16; ++c) {
    const int p = c & 1;
    if (c < 15) {
      const f32x4* pp = (const f32x4*)(xrow + (c + 1) * 64);
      xn[0] = pp[0]; xn[1] = pp[1]; xn[2] = pp[2]; xn[3] = pp[3];
      issue_B(c + 1, p ^ 1);
    }
    compute(p);
    if (c < 15) {
      __builtin_amdgcn_s_waitcnt(0);   // drain x regs + gl_lds before LDS write
      write_A(p ^ 1, xn);
    }
    __syncthreads();
  }

  // ---- epilogue: C-layout (col=lane&15, row=quad*4+r); split-store q,k ----
  const int strip = wave * 16;
#pragma unroll
  for (int j = 0; j < 12; ++j) {
    const int n  = j * 16 + l15;
    const int mm = n >> 6;     // 0=q,1=k,2=v (uniform per j)
    const int h  = n & 63;
#pragma unroll
    for (int r = 0; r < 4; ++r) {
      const int trow = row0 + strip + l4 * 4 + r;
      const float val = acc[j][r];
      const __hip_bfloat16 hi = __float2bfloat16(val);
      const __hip_bfloat16 lo = __float2bfloat16(val - __bfloat162float(hi));
      if (mm == 0) {
        qhi[trow * 64 + h] = hi;
        qlo[trow * 64 + h] = lo;
      } else if (mm == 1) {
        khi[trow * 64 + h] = hi;
        klo[trow * 64 + h] = lo;
      } else {
        const int bb = trow >> 11, tl = trow & 2047;
        vT[(bb * 64 + h) * 2048 + tl] = hi;
      }
    }
  }
}

// ---------------------------------------------------------------------------
// Kernel B: flash attention, causal, no score scaling. Split-bf16 QK^T:
// S = qh*kh + qh*kl + ql*kh (fp32-accurate scores). 1 wave/block, 16 Q-rows,
// grid = 8*128 reversed. K-tile=64 staged via gl_lds with XOR swizzle.
// ---------------------------------------------------------------------------
__global__ __launch_bounds__(64) void attn(
    const __hip_bfloat16* __restrict__ qhi, const __hip_bfloat16* __restrict__ qlo,
    const __hip_bfloat16* __restrict__ khi, const __hip_bfloat16* __restrict__ klo,
    const __hip_bfloat16* __restrict__ vT, float* __restrict__ out) {
  __shared__ __hip_bfloat16 Khi[64 * 64];   // [key][h], swizzled 16B groups
  __shared__ __hip_bfloat16 Klo[64 * 64];
  __shared__ __hip_bfloat16 Vsm[64 * 64];   // [h][key], swizzled 16B groups
  __shared__ __hip_bfloat16 Psm[16 * 72];   // [t][key], padded (+8)

  const int lane  = threadIdx.x;
  const int bid   = blockIdx.x;
  const int b     = bid >> 7;
  const int strip = 127 - (bid & 127);      // big-work blocks first
  const int t0    = strip * 16;
  const int l15 = lane & 15, l4 = lane >> 4;

  // Q A-frags (A[m=lane&15][k=quad*8+j]), hi+lo, held in regs for all K-tiles
  const __hip_bfloat16* qph = qhi + (b * 2048 + t0 + l15) * 64;
  const __hip_bfloat16* qpl = qlo + (b * 2048 + t0 + l15) * 64;
  short8 qh0 = *(const short8*)(qph + l4 * 8);
  short8 qh1 = *(const short8*)(qph + 32 + l4 * 8);
  short8 ql0 = *(const short8*)(qpl + l4 * 8);
  short8 ql1 = *(const short8*)(qpl + 32 + l4 * 8);

  f32x4 acc[4];
#pragma unroll
  for (int j = 0; j < 4; ++j) acc[j] = f32x4{0.f, 0.f, 0.f, 0.f};
  float m_[4] = {-1e30f, -1e30f, -1e30f, -1e30f};
  float l_[4] = {0.f, 0.f, 0.f, 0.f};

  const int sub = lane >> 3;        // 0..7
  const int gsw = (lane & 7) ^ sub; // row&7 == sub for 8-row chunks

  const int ktiles = ((t0 + 15) >> 6) + 1;
  for (int kt = 0; kt < ktiles; ++kt) {
    const int k0 = kt << 6;
    // ---- stage K hi/lo (rows=key, cols=h) and V (rows=h, cols=key) ----
#pragma unroll
    for (int c = 0; c < 8; ++c) {
      const int key = k0 + c * 8 + sub;
      gload_lds16(khi + (b * 2048 + key) * 64 + gsw * 8, &Khi[c * 512]);
      gload_lds16(klo + (b * 2048 + key) * 64 + gsw * 8, &Klo[c * 512]);
    }
#pragma unroll
    for (int c = 0; c < 8; ++c) {
      const int h = c * 8 + sub;
      gload_lds16(vT + (b * 64 + h) * 2048 + k0 + gsw * 8, &Vsm[c * 512]);
    }
    __builtin_amdgcn_s_waitcnt(0);   // gl_lds -> ds_read dependency

    // ---- S = Q K^T (split precision) over this 64-key tile ----
    f32x4 s[4];
#pragma unroll
    for (int j = 0; j < 4; ++j) {
      const int key = j * 16 + l15;
      const int o0  = ((l4)     ^ (key & 7)) * 8;
      const int o1  = ((4 + l4) ^ (key & 7)) * 8;
      short8 kh0 = *(const short8*)&Khi[key * 64 + o0];
      short8 kh1 = *(const short8*)&Khi[key * 64 + o1];
      short8 kl0 = *(const short8*)&Klo[key * 64 + o0];
      short8 kl1 = *(const short8*)&Klo[key * 64 + o1];
      f32x4 z = f32x4{0.f, 0.f, 0.f, 0.f};
      z = mfma_16x16x32(qh0, kh0, z);
      z = mfma_16x16x32(qh1, kh1, z);
      z = mfma_16x16x32(qh0, kl0, z);
      z = mfma_16x16x32(qh1, kl1, z);
      z = mfma_16x16x32(ql0, kh0, z);
      z = mfma_16x16x32(ql1, kh1, z);
      s[j] = z;
    }

    // ---- causal mask (only tiles touching the diagonal) ----
    if (k0 + 63 > t0) {
#pragma unroll
      for (int j = 0; j < 4; ++j) {
        const int key = k0 + j * 16 + l15;
#pragma unroll
        for (int r = 0; r < 4; ++r) {
          const int row = t0 + l4 * 4 + r;
          if (key > row) s[j][r] = -1e30f;
        }
      }
    }

    // ---- online softmax (4 rows/lane; reduce across 16-lane col groups) ----
    float mx[4], rs[4], al[4];
#pragma unroll
    for (int r = 0; r < 4; ++r)
      mx[r] = fmaxf(fmaxf(s[0][r], s[1][r]), fmaxf(s[2][r], s[3][r]));
    for (int off = 1; off < 16; off <<= 1) {
#pragma unroll
      for (int r = 0; r < 4; ++r) mx[r] = fmaxf(mx[r], __shfl_xor(mx[r], off));
    }
#pragma unroll
    for (int r = 0; r < 4; ++r) {
      const float mn = fmaxf(m_[r], mx[r]);
      al[r] = __expf(m_[r] - mn);
      m_[r] = mn;
      rs[r] = 0.f;
    }
#pragma unroll
    for (int j = 0; j < 4; ++j) {
#pragma unroll
      for (int r = 0; r < 4; ++r) {
        const float pv = __expf(s[j][r] - m_[r]);
        s[j][r] = pv;
        rs[r] += pv;
      }
    }
    for (int off = 1; off < 16; off <<= 1) {
#pragma unroll
      for (int r = 0; r < 4; ++r) rs[r] += __shfl_xor(rs[r], off);
    }
#pragma unroll
    for (int r = 0; r < 4; ++r) l_[r] = l_[r] * al[r] + rs[r];
#pragma unroll
    for (int j = 0; j < 4; ++j) {
#pragma unroll
      for (int r = 0; r < 4; ++r) acc[j][r] *= al[r];
    }

    // ---- P: C-layout -> LDS -> A-layout ----
#pragma unroll
    for (int j = 0; j < 4; ++j) {
#pragma unroll
      for (int r = 0; r < 4; ++r)
        Psm[(l4 * 4 + r) * 72 + j * 16 + l15] = __float2bfloat16(s[j][r]);
    }
    __builtin_amdgcn_s_waitcnt(0);   // same-wave LDS write->read visibility
    short8 pf0 = *(const short8*)&Psm[l15 * 72 + l4 * 8];
    short8 pf1 = *(const short8*)&Psm[l15 * 72 + 32 + l4 * 8];

    // ---- O += P V ----
#pragma unroll
    for (int j = 0; j < 4; ++j) {
      const int h  = j * 16 + l15;
      const int o0 = ((l4)     ^ (h & 7)) * 8;
      const int o1 = ((4 + l4) ^ (h & 7)) * 8;
      short8 vf0 = *(const short8*)&Vsm[h * 64 + o0];
      short8 vf1 = *(const short8*)&Vsm[h * 64 + o1];
      acc[j] = mfma_16x16x32(pf0, vf0, acc[j]);
      acc[j] = mfma_16x16x32(pf1, vf1, acc[j]);
    }
  }

  // ---- epilogue: normalize, store fp32 ----
  float inv[4];
#pragma unroll
  for (int r = 0; r < 4; ++r) inv[r] = 1.f / l_[r];
  float* op = out + (b * 2048 + t0) * 64;
#pragma unroll
  for (int j = 0; j < 4; ++j) {
#pragma unroll
    for (int r = 0; r < 4; ++r)
      op[(l4 * 4 + r) * 64 + j * 16 + l15] = acc[j][r] * inv[r];
  }
}

// ---------------------------------------------------------------------------
extern "C" void kernel_launch(void* const* d_in, const int* in_sizes, int n_in,
                              void* d_out, int out_size, void* d_ws, size_t ws_size,
                              hipStream_t stream) {
  const float* x  = (const float*)d_in[0];
  const float* Wq = (const float*)d_in[1];
  const float* Wk = (const float*)d_in[2];
  const float* Wv = (const float*)d_in[3];
  float* out = (float*)d_out;

  char* ws = (char*)d_ws;
  __hip_bfloat16* Wthi = (__hip_bfloat16*)ws;                   // 384 KB
  __hip_bfloat16* Wtlo = (__hip_bfloat16*)(ws + 393216);        // 384 KB
  __hip_bfloat16* qhi  = (__hip_bfloat16*)(ws + 786432);        // 2 MB each
  __hip_bfloat16* qlo  = (__hip_bfloat16*)(ws + 786432 + 1 * 2097152);
  __hip_bfloat16* khi  = (__hip_bfloat16*)(ws + 786432 + 2 * 2097152);
  __hip_bfloat16* klo  = (__hip_bfloat16*)(ws + 786432 + 3 * 2097152);
  __hip_bfloat16* vT   = (__hip_bfloat16*)(ws + 786432 + 4 * 2097152);

  prep_w<<<192, 256, 0, stream>>>(Wq, Wk, Wv, Wthi, Wtlo);
  qkv_gemm<<<256, 256, 0, stream>>>(x, Wthi, Wtlo, qhi, qlo, khi, klo, vT);
  attn<<<BB * (TT / 16), 64, 0, stream>>>(qhi, qlo, khi, klo, vT, out);
}